// Round 7
// baseline (441.363 us; speedup 1.0000x reference)
//
#include <hip/hip_runtime.h>
#include <hip/hip_bf16.h>
#include <math.h>

#define TT 1024
#define KK 128
#define BB 512
#define TPB 256

typedef float v2f __attribute__((ext_vector_type(2)));

// pad 4 floats per 16: slice o starts at float 20*o -> distinct banks; 80B*o
// is 16B-aligned. Verified conflict-free (R5/R6: SQ_LDS_BANK_CONFLICT = 0).
__device__ __forceinline__ int padidx(int f) { return f + ((f >> 4) << 2); }

// VALU-latency cross-lane via DPP.
template <int CTRL>
__device__ __forceinline__ float dppf(float x) {
    union { float f; int i; } u, o;
    u.f = x;
    o.i = __builtin_amdgcn_update_dpp(0, u.i, CTRL, 0xF, 0xF, false);
    return o.f;
}
#define DPP_XOR1 0xB1   // quad_perm [1,0,3,2]  : lane ^= 1
#define DPP_XOR2 0x4E   // quad_perm [2,3,0,1]  : lane ^= 2
#define DPP_XOR8 0x128  // row_ror:8            : lane ^= 8

// Barrier that drains ONLY LDS ops (lgkmcnt), leaving HBM prefetches in
// flight (__syncthreads would s_waitcnt vmcnt(0) and put ~600 cyc of HBM
// latency on the serial chain every step).
#define LDS_BARRIER() asm volatile("s_waitcnt lgkmcnt(0)\n\ts_barrier" ::: "memory")

// Scaled CRF forward (exp-space):
//   v_{t+1} = (E . v_t) * exp(feat_t) * r_t, r_t = rcp(v_t[tag0]) (published
//   one step earlier), La accumulates -log(r_t) off-chain.
// 512 blocks x 256 threads; thread (g,o) owns E[g*4..g*4+3][o*16..o*16+16).
// Per step (ONE lgkm-only barrier): 4x ds_read_b128 -> 32 pk_fma (depth 4) ->
// 3 DPP folds -> v' = u*ef*r -> ds_write -> barrier.
__global__ __launch_bounds__(TPB, 2)
void crf_fwd_kernel(const float* __restrict__ feats,
                    const float* __restrict__ trans,
                    float* __restrict__ out)
{
    const int b    = blockIdx.x;
    const int tid  = threadIdx.x;
    const int lane = tid & 63;
    const int wave = tid >> 6;
    const int o    = (lane & 3) | (((lane >> 3) & 1) << 2);           // slice
    const int g    = ((lane >> 2) & 1) | (((lane >> 4) & 3) << 1) | (wave << 3);
    const int rr   = ((o & 1) << 1) | ((o >> 1) & 1);
    const int tag  = (g << 2) + rr;       // tag finalized here (dup over o&4)
    const bool wr  = (o & 4) == 0;        // writer copy of the dup pair

    __shared__ __align__(16) float v_lds[2][160];
    __shared__ float rslot[2];
    __shared__ float sred[4];

    // ---- E tile: rows g*4+r, frm slice [o*16, o*16+16) : 64 floats ----
    v2f E2[4][8];
    #pragma unroll
    for (int r = 0; r < 4; ++r) {
        const float4* tr = reinterpret_cast<const float4*>(trans + (g * 4 + r) * KK + o * 16);
        #pragma unroll
        for (int i = 0; i < 4; ++i) {
            float4 v = tr[i];
            E2[r][2 * i + 0] = v2f{__expf(v.x), __expf(v.y)};
            E2[r][2 * i + 1] = v2f{__expf(v.z), __expf(v.w)};
        }
    }
    const float eEnd = __expf(trans[(KK - 2) * KK + tag]);

    // 3-deep feat pipeline: ef=exp(feat[t]); fA=feat[t+1]; fB=feat[t+2]
    const float* fp = feats + (size_t)b * TT * KK + tag;
    float f0 = fp[0];
    float fA = fp[KK];
    float fB = fp[2 * KK];
    fp += 3 * KK;
    float ef = __expf(f0);

    // init: v_0 = e_START (START = K-1), r_0 = 1
    if (tid == 0) rslot[0] = 1.0f;
    if (wr) v_lds[0][padidx(tag)] = (tag == KK - 1) ? 1.0f : 0.0f;
    __syncthreads();

    float La = 0.0f;   // -sum log r_t (uniform across threads)
    float vv = 0.0f;   // this thread's v_T[tag] after the loop

    for (int t = 0; t < TT; ++t) {
        const int buf = t & 1;

        // ---- off-chain: feat[t+3] load + exp(feat[t+1]) ----
        float fC = 0.0f;
        if (t + 3 < TT) fC = *fp;
        fp += KK;
        const float ef_next = __expf(fA);

        const float r = rslot[buf];        // published last step

        // ---- u partials: 4 rows x 16 frm, 2 accum chains per row ----
        const float* pbase = &v_lds[buf][o * 20];
        v2f a0 = {0.f,0.f}, a1 = {0.f,0.f}, a2 = {0.f,0.f}, a3 = {0.f,0.f};
        v2f b0 = {0.f,0.f}, b1 = {0.f,0.f}, b2 = {0.f,0.f}, b3 = {0.f,0.f};
        #pragma unroll
        for (int i = 0; i < 4; ++i) {
            float4 pq = *reinterpret_cast<const float4*>(pbase + i * 4);
            v2f plo = v2f{pq.x, pq.y};
            v2f phi = v2f{pq.z, pq.w};
            a0 = __builtin_elementwise_fma(E2[0][2 * i], plo, a0);
            a1 = __builtin_elementwise_fma(E2[1][2 * i], plo, a1);
            a2 = __builtin_elementwise_fma(E2[2][2 * i], plo, a2);
            a3 = __builtin_elementwise_fma(E2[3][2 * i], plo, a3);
            b0 = __builtin_elementwise_fma(E2[0][2 * i + 1], phi, b0);
            b1 = __builtin_elementwise_fma(E2[1][2 * i + 1], phi, b1);
            b2 = __builtin_elementwise_fma(E2[2][2 * i + 1], phi, b2);
            b3 = __builtin_elementwise_fma(E2[3][2 * i + 1], phi, b3);
        }
        v2f c0 = a0 + b0, c1 = a1 + b1, c2 = a2 + b2, c3 = a3 + b3;
        float s0 = c0.x + c0.y;
        float s1 = c1.x + c1.y;
        float s2 = c2.x + c2.y;
        float s3 = c3.x + c3.y;

        // ---- exchange-split combine on lane bits {0,1,3} via DPP ----
        float send_lo = (o & 1) ? s0 : s2;
        float send_hi = (o & 1) ? s1 : s3;
        float recv_lo = dppf<DPP_XOR1>(send_lo);
        float recv_hi = dppf<DPP_XOR1>(send_hi);
        float qa = ((o & 1) ? s2 : s0) + recv_lo;
        float qb = ((o & 1) ? s3 : s1) + recv_hi;
        float send2 = (o & 2) ? qa : qb;
        float recv2 = dppf<DPP_XOR2>(send2);
        float sv = ((o & 2) ? qb : qa) + recv2;
        sv += dppf<DPP_XOR8>(sv);                   // full u[tag]

        // ---- v' = u * ef * r ; bookkeeping off-chain ----
        vv = sv * ef * r;
        La -= __logf(r);

        if (tid == 0) rslot[buf ^ 1] = __builtin_amdgcn_rcpf(vv);  // r for t+1
        if (wr) v_lds[buf ^ 1][padidx(tag)] = vv;

        LDS_BARRIER();                     // lgkm-only: HBM prefetch stays in flight

        ef = ef_next;
        fA = fB;
        fB = fC;
    }

    // ---- out[b] = La + log( sum_tag v_T[tag] * exp(trans[END][tag]) ) ----
    float e = wr ? vv * eEnd : 0.0f;
    #pragma unroll
    for (int s = 32; s >= 1; s >>= 1)
        e += __shfl_xor(e, s, 64);
    if (lane == 0) sred[wave] = e;
    __syncthreads();
    if (tid == 0)
        out[b] = La + __logf((sred[0] + sred[1]) + (sred[2] + sred[3]));
}

extern "C" void kernel_launch(void* const* d_in, const int* in_sizes, int n_in,
                              void* d_out, int out_size, void* d_ws, size_t ws_size,
                              hipStream_t stream) {
    const float* feats = (const float*)d_in[0];  // [B, T, K] f32
    const float* trans = (const float*)d_in[1];  // [K, K] f32
    float* out = (float*)d_out;                  // [B] f32

    crf_fwd_kernel<<<BB, TPB, 0, stream>>>(feats, trans, out);
}